// Round 1
// baseline (19644.226 us; speedup 1.0000x reference)
//
#include <hip/hip_runtime.h>

// ---------------------------------------------------------------------------
// Bayesian LSTM forward: B=256, L=512, K=128, H=512 (4H = 2048)
//
// Decomposition: 256 persistent blocks (1 per CU, cooperative launch).
//   group g (0..15)  = 16 batch rows [16g, 16g+16)
//   slice s (0..15)  = 32 hidden units [32s, 32s+32)  -> 128 gate cols
// Block (g,s): per step t, GEMM [16 x 640] x [640 x 128] (h|x concat on K),
// weights stationary in VGPRs (40 bf16x8 B-frags / wave; wave w = gate w).
// h exchanged between the 16 blocks of a group via bf16 L2 buffer + flag sync
// (device-scope atomics + fences -> correct regardless of XCD placement).
// c stays in fp32 registers inside the block (never communicated).
// ---------------------------------------------------------------------------

typedef __attribute__((ext_vector_type(8))) __bf16 bf16x8;
typedef __attribute__((ext_vector_type(4))) float f32x4;
typedef __attribute__((ext_vector_type(8))) unsigned short us8;

union U8 { us8 v; unsigned short u[8]; };

#define WFRAG_OFF   0u           // 1310720 ushort = 2621440 B
#define HBUF_OFF    2621440u     // 2*256*512 ushort = 524288 B
#define FLAGS_OFF   3145728u     // 512*16 int = 32768 B
#define PART_OFF    3178496u     // 512 float = 2048 B
#define WS_NEEDED   3180544u

#define LOSS_OFF    67108864u
#define HT_OFF      67108865u
#define CT_OFF      67239937u

__device__ __forceinline__ unsigned short f2bf(float f) {
  unsigned int u = __builtin_bit_cast(unsigned int, f);
  unsigned int r = (u + 0x7FFFu + ((u >> 16) & 1u)) >> 16;
  return (unsigned short)r;
}

__device__ __forceinline__ float sigm(float v) {
  return __builtin_amdgcn_rcpf(1.0f + __expf(-v));
}
__device__ __forceinline__ float tanh_f(float v) {
  return 1.0f - 2.0f * __builtin_amdgcn_rcpf(__expf(2.0f * v) + 1.0f);
}

// ---------------- prep: weight fragments (bf16, MFMA B layout) + zero flags --
// Layout: gid = ((s*160 + w*40 + fr)*64 + lane), elem j (0..7):
//   fr = ct*20 + kt;  k = 32*kt + 8*(lane>>4) + j (k<512: whh row, else wih)
//   gc = 512*w + 32*s + 16*ct + (lane&15)
__global__ void prep_w(const float* __restrict__ whh, const float* __restrict__ wih,
                       unsigned short* __restrict__ w_frag, int* __restrict__ flags) {
  int gid = blockIdx.x * 256 + threadIdx.x;
  if (gid < 8192) flags[gid] = 0;
  if (gid >= 163840) return;
  int lane = gid & 63;
  int t3 = gid >> 6;
  int fr = t3 % 40;
  int w  = (t3 / 40) & 3;
  int s  = t3 / 160;
  int kt = fr % 20, ct = fr / 20;
  int gc = (w << 9) + (s << 5) + (ct << 4) + (lane & 15);
  int kbase = (kt << 5) + ((lane >> 4) << 3);
  U8 p;
#pragma unroll
  for (int j = 0; j < 8; ++j) {
    int k = kbase + j;
    float v = (k < 512) ? whh[k * 2048 + gc] : wih[(k - 512) * 2048 + gc];
    p.u[j] = f2bf(v);
  }
  *(us8*)&w_frag[(size_t)gid * 8] = p.v;
}

// ---------------- bayes loss: block partials ---------------------------------
__global__ void loss_k(const float* __restrict__ whh, const float* __restrict__ wih,
                       const float* __restrict__ bias,
                       const float* __restrict__ whh_mu, const float* __restrict__ whh_rho,
                       const float* __restrict__ wih_mu, const float* __restrict__ wih_rho,
                       const float* __restrict__ b_mu, const float* __restrict__ b_rho,
                       float* __restrict__ partials) {
  int gid = blockIdx.x * 256 + threadIdx.x;
  float acc = 0.f;
  for (int idx = gid; idx < 1312768; idx += 131072) {
    float p, mu, rho;
    if (idx < 1048576)      { p = whh[idx];           mu = whh_mu[idx];           rho = whh_rho[idx]; }
    else if (idx < 1310720) { int i = idx - 1048576;  p = wih[i]; mu = wih_mu[i]; rho = wih_rho[i]; }
    else                    { int i = idx - 1310720;  p = bias[i]; mu = b_mu[i];  rho = b_rho[i]; }
    float sig = log1pf(__expf(rho));
    float d = p - mu;
    float vari = -0.57236494f - logf(sig) - d * d / (2.f * sig * sig);
    float lp1 = -0.91893853f - 0.5f * p * p;
    float lp2 = 5.98881675f - 500000.f * p * p;
    float prior = logf(0.5f * (__expf(lp1) + __expf(lp2)));
    acc += vari - prior;
  }
#pragma unroll
  for (int off = 32; off; off >>= 1) acc += __shfl_down(acc, off, 64);
  __shared__ float wsum[4];
  if ((threadIdx.x & 63) == 0) wsum[threadIdx.x >> 6] = acc;
  __syncthreads();
  if (threadIdx.x == 0) partials[blockIdx.x] = wsum[0] + wsum[1] + wsum[2] + wsum[3];
}

// ---------------- persistent LSTM kernel -------------------------------------
__launch_bounds__(256, 1)
__global__ void lstm_k(const float* __restrict__ x,
                       const unsigned short* __restrict__ w_frag,
                       const float* __restrict__ bias,
                       unsigned short* __restrict__ h_buf,
                       int* __restrict__ flags,
                       const float* __restrict__ partials,
                       float* __restrict__ out) {
  __shared__ unsigned short A_sh[16][648];   // [row][k] h(0..512)|x(512..640), pad 648
  __shared__ float gates_sh[16][132];        // [row][32*gate + unit_off], pad 132

  const int tid  = threadIdx.x;
  const int lane = tid & 63;
  const int wv   = tid >> 6;                 // 0..3 == gate chunk (i,f,g,o)
  const int bid  = blockIdx.x;
  // XCD-local group swizzle (perf heuristic only)
  const int xcd = bid & 7;
  const int idx = bid >> 3;
  const int g = (xcd << 1) | (idx & 1);      // batch group 0..15
  const int s = idx >> 1;                    // hidden slice 0..15
  const int b0 = g << 4;

  // --- stationary B fragments: 40 x bf16x8 (ct*20 + kt) -------------------
  us8 bfr[40];
  {
    const us8* wfp = (const us8*)(w_frag + (size_t)s * 81920);
#pragma unroll
    for (int fr = 0; fr < 40; ++fr)
      bfr[fr] = wfp[(wv * 40 + fr) * 64 + lane];
  }

  // --- epilogue mapping: thread -> (row r, units u0=2*up, u0+1) ------------
  const int r  = tid >> 4;                   // 0..15
  const int uo = (tid & 15) << 1;            // 0..30 (unit offset in slice)
  const int ug = (s << 5) + uo;              // global hidden unit
  const float bi0 = bias[ug],        bi1 = bias[ug + 1];
  const float bf0 = bias[512 + ug],  bf1 = bias[512 + ug + 1];
  const float bg0 = bias[1024 + ug], bg1 = bias[1024 + ug + 1];
  const float bo0 = bias[1536 + ug], bo1 = bias[1536 + ug + 1];
  float c0 = 0.f, c1 = 0.f;

  const unsigned short* arow = &A_sh[lane & 15][(lane >> 4) << 3];

  for (int t = 0; t < 512; ++t) {
    // ---- stage x_t (fp32 -> bf16) into A_sh[.][512..640] (flag-independent)
    {
      const int xrow = tid >> 4;
      const int f8 = (tid & 15) << 3;
      const float* xp = x + ((((size_t)(b0 + xrow) << 9) + t) << 7) + f8;
      float4 va = *(const float4*)xp;
      float4 vb = *(const float4*)(xp + 4);
      U8 p;
      p.u[0] = f2bf(va.x); p.u[1] = f2bf(va.y); p.u[2] = f2bf(va.z); p.u[3] = f2bf(va.w);
      p.u[4] = f2bf(vb.x); p.u[5] = f2bf(vb.y); p.u[6] = f2bf(vb.z); p.u[7] = f2bf(vb.w);
      *(us8*)&A_sh[xrow][512 + f8] = p.v;
    }

    if (t > 0) {
      // ---- wait for all 16 blocks of the group to publish h_t ------------
      if (tid == 0) {
        const int fidx = ((t - 1) << 4) + g;
        while (__hip_atomic_load(&flags[fidx], __ATOMIC_RELAXED,
                                 __HIP_MEMORY_SCOPE_AGENT) < 16)
          __builtin_amdgcn_s_sleep(1);
      }
      __syncthreads();
      __threadfence();   // acquire: invalidate stale h_buf lines (all threads)
      // ---- stage h_t (bf16) into A_sh[.][0..512] -------------------------
      const unsigned short* hb = h_buf + ((size_t)(t & 1) << 17);
#pragma unroll
      for (int it = 0; it < 4; ++it) {
        int cid = (it << 8) + tid;
        int rr = cid >> 6;
        int cc = (cid & 63) << 3;
        *(us8*)&A_sh[rr][cc] = *(const us8*)&hb[((size_t)(b0 + rr) << 9) + cc];
      }
    }
    __syncthreads();

    // ---- GEMM: gates[16 x 32(wave cols)] += A[16 x 640] * B ---------------
    f32x4 acc0 = {0.f, 0.f, 0.f, 0.f}, acc1 = {0.f, 0.f, 0.f, 0.f};
    if (t > 0) {
      us8 areg[20];
#pragma unroll
      for (int kt = 0; kt < 20; ++kt)
        areg[kt] = *(const us8*)(arow + (kt << 5));
#pragma unroll
      for (int kt = 0; kt < 20; ++kt) {
        acc0 = __builtin_amdgcn_mfma_f32_16x16x32_bf16(
            __builtin_bit_cast(bf16x8, areg[kt]), __builtin_bit_cast(bf16x8, bfr[kt]), acc0, 0, 0, 0);
        acc1 = __builtin_amdgcn_mfma_f32_16x16x32_bf16(
            __builtin_bit_cast(bf16x8, areg[kt]), __builtin_bit_cast(bf16x8, bfr[20 + kt]), acc1, 0, 0, 0);
      }
    } else {  // h_0 = 0: only the x k-tiles (16..19)
#pragma unroll
      for (int kt = 16; kt < 20; ++kt) {
        us8 a = *(const us8*)(arow + (kt << 5));
        acc0 = __builtin_amdgcn_mfma_f32_16x16x32_bf16(
            __builtin_bit_cast(bf16x8, a), __builtin_bit_cast(bf16x8, bfr[kt]), acc0, 0, 0, 0);
        acc1 = __builtin_amdgcn_mfma_f32_16x16x32_bf16(
            __builtin_bit_cast(bf16x8, a), __builtin_bit_cast(bf16x8, bfr[20 + kt]), acc1, 0, 0, 0);
      }
    }

    // ---- scatter gates to LDS (C layout: col=lane&15, row=4*(lane>>4)+q) --
    {
      const int crow = (lane >> 4) << 2;
      const int ccol = lane & 15;
#pragma unroll
      for (int q = 0; q < 4; ++q) {
        gates_sh[crow + q][(wv << 5) + ccol]      = acc0[q];
        gates_sh[crow + q][(wv << 5) + 16 + ccol] = acc1[q];
      }
    }
    __syncthreads();

    // ---- gate math for 2 units of one row ---------------------------------
    float gi = gates_sh[r][uo] + bi0;
    float gf = gates_sh[r][32 + uo] + bf0;
    float gg = gates_sh[r][64 + uo] + bg0;
    float go = gates_sh[r][96 + uo] + bo0;
    float it_ = sigm(gi), ft_ = sigm(gf), ot_ = sigm(go);
    c0 = ft_ * c0 + it_ * tanh_f(gg);
    float h0 = ot_ * tanh_f(c0);

    gi = gates_sh[r][uo + 1] + bi1;
    gf = gates_sh[r][32 + uo + 1] + bf1;
    gg = gates_sh[r][64 + uo + 1] + bg1;
    go = gates_sh[r][96 + uo + 1] + bo1;
    it_ = sigm(gi); ft_ = sigm(gf); ot_ = sigm(go);
    c1 = ft_ * c1 + it_ * tanh_f(gg);
    float h1 = ot_ * tanh_f(c1);

    // ---- writes: hidden_seq (fp32), h comm buffer (bf16) ------------------
    const size_t gb = (size_t)(b0 + r);
    float2 hv; hv.x = h0; hv.y = h1;
    *(float2*)&out[(((gb << 9) + t) << 9) + ug] = hv;
    unsigned short* hbn = h_buf + ((size_t)((t + 1) & 1) << 17);
    unsigned int pk = (unsigned int)f2bf(h0) | ((unsigned int)f2bf(h1) << 16);
    *(unsigned int*)&hbn[(gb << 9) + ug] = pk;
    if (t == 511) {
      float2 cv; cv.x = c0; cv.y = c1;
      *(float2*)&out[HT_OFF + (gb << 9) + ug] = hv;
      *(float2*)&out[CT_OFF + (gb << 9) + ug] = cv;
    }

    // ---- publish h_{t+1}: release fence + flag ----------------------------
    __threadfence();
    __syncthreads();
    if (tid == 0)
      __hip_atomic_fetch_add(&flags[(t << 4) + g], 1, __ATOMIC_RELEASE,
                             __HIP_MEMORY_SCOPE_AGENT);
  }

  // ---- block 0: finalize deterministic loss sum ---------------------------
  if (bid == 0) {
    float v = partials[tid] + partials[tid + 256];
#pragma unroll
    for (int off = 32; off; off >>= 1) v += __shfl_down(v, off, 64);
    __shared__ float lw[4];
    if ((tid & 63) == 0) lw[tid >> 6] = v;
    __syncthreads();
    if (tid == 0) out[LOSS_OFF] = lw[0] + lw[1] + lw[2] + lw[3];
  }
}

// ---------------------------------------------------------------------------
extern "C" void kernel_launch(void* const* d_in, const int* in_sizes, int n_in,
                              void* d_out, int out_size, void* d_ws, size_t ws_size,
                              hipStream_t stream) {
  if (ws_size < WS_NEEDED) return;
  const float* x       = (const float*)d_in[0];
  const float* whh     = (const float*)d_in[1];
  const float* wih     = (const float*)d_in[2];
  const float* bias    = (const float*)d_in[3];
  const float* whh_mu  = (const float*)d_in[4];
  const float* whh_rho = (const float*)d_in[5];
  const float* wih_mu  = (const float*)d_in[6];
  const float* wih_rho = (const float*)d_in[7];
  const float* b_mu    = (const float*)d_in[8];
  const float* b_rho   = (const float*)d_in[9];
  char* ws = (char*)d_ws;
  unsigned short* w_frag = (unsigned short*)(ws + WFRAG_OFF);
  unsigned short* h_buf  = (unsigned short*)(ws + HBUF_OFF);
  int*            flags  = (int*)(ws + FLAGS_OFF);
  float*          parts  = (float*)(ws + PART_OFF);
  float*          out    = (float*)d_out;

  prep_w<<<640, 256, 0, stream>>>(whh, wih, w_frag, flags);
  loss_k<<<512, 256, 0, stream>>>(whh, wih, bias, whh_mu, whh_rho,
                                  wih_mu, wih_rho, b_mu, b_rho, parts);

  void* kargs[7];
  kargs[0] = (void*)&x;
  kargs[1] = (void*)&w_frag;
  kargs[2] = (void*)&bias;
  kargs[3] = (void*)&h_buf;
  kargs[4] = (void*)&flags;
  kargs[5] = (void*)&parts;
  kargs[6] = (void*)&out;
  hipLaunchCooperativeKernel((const void*)lstm_k, dim3(256), dim3(256),
                             kargs, 0, stream);
}

// Round 2
// 1387.569 us; speedup vs baseline: 14.1573x; 14.1573x over previous
//
#include <hip/hip_runtime.h>

// ---------------------------------------------------------------------------
// Bayesian LSTM forward: B=256, L=512, K=128, H=512 (4H = 2048)
//
// 256 persistent blocks (1/CU, cooperative launch).
//   group g (0..15) = 16 batch rows; slice s (0..15) = 32 hidden units.
// Per step: GEMM [16 x 640] x [640 x 128], weights stationary in VGPR/AGPR.
// Cross-block h exchange is FENCE-FREE: all communication uses relaxed
// agent-scope atomics (global_load/store sc1 -> memory-side L3, the device
// coherence point). Visibility = vmcnt(0) drain + barrier before flag store.
// Flags: per-producer slots, step-tag values, ring of 4 (no reset, no RMW).
// ---------------------------------------------------------------------------

typedef __attribute__((ext_vector_type(8))) __bf16 bf16x8;
typedef __attribute__((ext_vector_type(4))) float f32x4;
typedef __attribute__((ext_vector_type(8))) unsigned short us8;

union U8 { us8 v; unsigned short u[8]; };

#define WFRAG_OFF   0u           // 1310720 ushort = 2621440 B
#define HBUF_OFF    2621440u     // 2*256*512 ushort = 524288 B
#define FLAGS_OFF   3145728u     // 4*16*16 int = 4096 B (ring of 4, tag=t+1)
#define PART_OFF    3178496u     // 512 float = 2048 B
#define WS_NEEDED   3180544u

#define LOSS_OFF    67108864u
#define HT_OFF      67108865u
#define CT_OFF      67239937u

__device__ __forceinline__ unsigned short f2bf(float f) {
  unsigned int u = __builtin_bit_cast(unsigned int, f);
  unsigned int r = (u + 0x7FFFu + ((u >> 16) & 1u)) >> 16;
  return (unsigned short)r;
}

__device__ __forceinline__ float sigm(float v) {
  return __builtin_amdgcn_rcpf(1.0f + __expf(-v));
}
__device__ __forceinline__ float tanh_f(float v) {
  return 1.0f - 2.0f * __builtin_amdgcn_rcpf(__expf(2.0f * v) + 1.0f);
}

// ---------------- prep: weight fragments (bf16, MFMA B layout) + zero flags --
__global__ void prep_w(const float* __restrict__ whh, const float* __restrict__ wih,
                       unsigned short* __restrict__ w_frag, int* __restrict__ flags) {
  int gid = blockIdx.x * 256 + threadIdx.x;
  if (gid < 1024) flags[gid] = 0;
  if (gid >= 163840) return;
  int lane = gid & 63;
  int t3 = gid >> 6;
  int fr = t3 % 40;
  int w  = (t3 / 40) & 3;
  int s  = t3 / 160;
  int kt = fr % 20, ct = fr / 20;
  int gc = (w << 9) + (s << 5) + (ct << 4) + (lane & 15);
  int kbase = (kt << 5) + ((lane >> 4) << 3);
  U8 p;
#pragma unroll
  for (int j = 0; j < 8; ++j) {
    int k = kbase + j;
    float v = (k < 512) ? whh[k * 2048 + gc] : wih[(k - 512) * 2048 + gc];
    p.u[j] = f2bf(v);
  }
  *(us8*)&w_frag[(size_t)gid * 8] = p.v;
}

// ---------------- bayes loss: block partials ---------------------------------
__global__ void loss_k(const float* __restrict__ whh, const float* __restrict__ wih,
                       const float* __restrict__ bias,
                       const float* __restrict__ whh_mu, const float* __restrict__ whh_rho,
                       const float* __restrict__ wih_mu, const float* __restrict__ wih_rho,
                       const float* __restrict__ b_mu, const float* __restrict__ b_rho,
                       float* __restrict__ partials) {
  int gid = blockIdx.x * 256 + threadIdx.x;
  float acc = 0.f;
  for (int idx = gid; idx < 1312768; idx += 131072) {
    float p, mu, rho;
    if (idx < 1048576)      { p = whh[idx];           mu = whh_mu[idx];           rho = whh_rho[idx]; }
    else if (idx < 1310720) { int i = idx - 1048576;  p = wih[i]; mu = wih_mu[i]; rho = wih_rho[i]; }
    else                    { int i = idx - 1310720;  p = bias[i]; mu = b_mu[i];  rho = b_rho[i]; }
    float sig = log1pf(__expf(rho));
    float d = p - mu;
    float vari = -0.57236494f - logf(sig) - d * d / (2.f * sig * sig);
    float lp1 = -0.91893853f - 0.5f * p * p;
    float lp2 = 5.98881675f - 500000.f * p * p;
    float prior = logf(0.5f * (__expf(lp1) + __expf(lp2)));
    acc += vari - prior;
  }
#pragma unroll
  for (int off = 32; off; off >>= 1) acc += __shfl_down(acc, off, 64);
  __shared__ float wsum[4];
  if ((threadIdx.x & 63) == 0) wsum[threadIdx.x >> 6] = acc;
  __syncthreads();
  if (threadIdx.x == 0) partials[blockIdx.x] = wsum[0] + wsum[1] + wsum[2] + wsum[3];
}

// ---------------- persistent LSTM kernel -------------------------------------
__launch_bounds__(256, 1)
__global__ void lstm_k(const float* __restrict__ x,
                       const unsigned short* __restrict__ w_frag,
                       const float* __restrict__ bias,
                       unsigned short* __restrict__ h_buf,
                       int* __restrict__ flags,
                       const float* __restrict__ partials,
                       float* __restrict__ out) {
  __shared__ unsigned short A_sh[16][648];   // [row][k] h(0..512)|x(512..640)
  __shared__ float gates_sh[16][132];        // [row][32*gate + unit_off]

  const int tid  = threadIdx.x;
  const int lane = tid & 63;
  const int wv   = tid >> 6;                 // gate chunk (i,f,g,o)
  const int bid  = blockIdx.x;
  const int xcd = bid & 7;
  const int idx = bid >> 3;
  const int g = (xcd << 1) | (idx & 1);      // batch group 0..15
  const int s = idx >> 1;                    // hidden slice 0..15
  const int b0 = g << 4;

  // --- stationary B fragments: 40 x bf16x8 ---------------------------------
  us8 bfr[40];
  {
    const us8* wfp = (const us8*)(w_frag + (size_t)s * 81920);
#pragma unroll
    for (int fr = 0; fr < 40; ++fr)
      bfr[fr] = wfp[(wv * 40 + fr) * 64 + lane];
  }

  // --- epilogue mapping: thread -> (row r, units uo, uo+1) -----------------
  const int r  = tid >> 4;
  const int uo = (tid & 15) << 1;
  const int ug = (s << 5) + uo;
  const float bi0 = bias[ug],        bi1 = bias[ug + 1];
  const float bf0 = bias[512 + ug],  bf1 = bias[512 + ug + 1];
  const float bg0 = bias[1024 + ug], bg1 = bias[1024 + ug + 1];
  const float bo0 = bias[1536 + ug], bo1 = bias[1536 + ug + 1];
  float c0 = 0.f, c1 = 0.f;

  const unsigned short* arow = &A_sh[lane & 15][(lane >> 4) << 3];

  for (int t = 0; t < 512; ++t) {
    // ---- stage x_t (fp32 -> bf16), flag-independent: overlaps the poll ----
    {
      const int xrow = tid >> 4;
      const int f8 = (tid & 15) << 3;
      const float* xp = x + ((((size_t)(b0 + xrow) << 9) + t) << 7) + f8;
      float4 va = *(const float4*)xp;
      float4 vb = *(const float4*)(xp + 4);
      U8 p;
      p.u[0] = f2bf(va.x); p.u[1] = f2bf(va.y); p.u[2] = f2bf(va.z); p.u[3] = f2bf(va.w);
      p.u[4] = f2bf(vb.x); p.u[5] = f2bf(vb.y); p.u[6] = f2bf(vb.z); p.u[7] = f2bf(vb.w);
      *(us8*)&A_sh[xrow][512 + f8] = p.v;
    }

    if (t > 0) {
      // ---- each wave polls the 16 producer tags (relaxed agent, sc1) -----
      const int* fl = flags + (((t - 1) & 3) << 8) + (g << 4);
      while (true) {
        int f = (lane < 16)
            ? __hip_atomic_load(fl + lane, __ATOMIC_RELAXED, __HIP_MEMORY_SCOPE_AGENT)
            : t;
        if (__all(f == t)) break;
        __builtin_amdgcn_s_sleep(1);
      }
      // ---- stage h_t: 8x 8B sc1 loads into temps, then LDS writes --------
      const unsigned long long* hb =
          (const unsigned long long*)(h_buf + ((size_t)(t & 1) << 17));
      unsigned long long tmp[8];
#pragma unroll
      for (int it = 0; it < 8; ++it) {
        int c = (it << 8) + tid;                 // 0..2047
        tmp[it] = __hip_atomic_load(hb + (((size_t)(b0 + (c >> 7))) << 6) + (c & 127),
                                    __ATOMIC_RELAXED, __HIP_MEMORY_SCOPE_AGENT);
      }
#pragma unroll
      for (int it = 0; it < 8; ++it) {
        int c = (it << 8) + tid;
        *(unsigned long long*)&A_sh[c >> 7][(c & 127) << 2] = tmp[it];
      }
    }
    __syncthreads();

    // ---- GEMM: gates[16 x 32(wave cols)] += A[16 x 640] * B ---------------
    f32x4 acc0 = {0.f, 0.f, 0.f, 0.f}, acc1 = {0.f, 0.f, 0.f, 0.f};
    if (t > 0) {
      us8 areg[20];
#pragma unroll
      for (int kt = 0; kt < 20; ++kt)
        areg[kt] = *(const us8*)(arow + (kt << 5));
#pragma unroll
      for (int kt = 0; kt < 20; ++kt) {
        acc0 = __builtin_amdgcn_mfma_f32_16x16x32_bf16(
            __builtin_bit_cast(bf16x8, areg[kt]), __builtin_bit_cast(bf16x8, bfr[kt]), acc0, 0, 0, 0);
        acc1 = __builtin_amdgcn_mfma_f32_16x16x32_bf16(
            __builtin_bit_cast(bf16x8, areg[kt]), __builtin_bit_cast(bf16x8, bfr[20 + kt]), acc1, 0, 0, 0);
      }
    } else {  // h_0 = 0: only the x k-tiles
#pragma unroll
      for (int kt = 16; kt < 20; ++kt) {
        us8 a = *(const us8*)(arow + (kt << 5));
        acc0 = __builtin_amdgcn_mfma_f32_16x16x32_bf16(
            __builtin_bit_cast(bf16x8, a), __builtin_bit_cast(bf16x8, bfr[kt]), acc0, 0, 0, 0);
        acc1 = __builtin_amdgcn_mfma_f32_16x16x32_bf16(
            __builtin_bit_cast(bf16x8, a), __builtin_bit_cast(bf16x8, bfr[20 + kt]), acc1, 0, 0, 0);
      }
    }

    // ---- scatter gates to LDS (C layout: col=lane&15, row=4*(lane>>4)+q) --
    {
      const int crow = (lane >> 4) << 2;
      const int ccol = lane & 15;
#pragma unroll
      for (int q = 0; q < 4; ++q) {
        gates_sh[crow + q][(wv << 5) + ccol]      = acc0[q];
        gates_sh[crow + q][(wv << 5) + 16 + ccol] = acc1[q];
      }
    }
    __syncthreads();

    // ---- gate math for 2 units of one row ---------------------------------
    float2 vi = *(const float2*)&gates_sh[r][uo];
    float2 vf = *(const float2*)&gates_sh[r][32 + uo];
    float2 vg = *(const float2*)&gates_sh[r][64 + uo];
    float2 vo = *(const float2*)&gates_sh[r][96 + uo];
    float it0 = sigm(vi.x + bi0), ft0 = sigm(vf.x + bf0), ot0 = sigm(vo.x + bo0);
    c0 = ft0 * c0 + it0 * tanh_f(vg.x + bg0);
    float h0 = ot0 * tanh_f(c0);
    float it1 = sigm(vi.y + bi1), ft1 = sigm(vf.y + bf1), ot1 = sigm(vo.y + bo1);
    c1 = ft1 * c1 + it1 * tanh_f(vg.y + bg1);
    float h1 = ot1 * tanh_f(c1);

    // ---- publish h_{t+1}: sc1 store -> drain -> barrier -> tag ------------
    const size_t gb = (size_t)(b0 + r);
    unsigned short* hbn = h_buf + ((size_t)((t + 1) & 1) << 17);
    unsigned int pk = (unsigned int)f2bf(h0) | ((unsigned int)f2bf(h1) << 16);
    __hip_atomic_store((unsigned int*)&hbn[(gb << 9) + ug], pk,
                       __ATOMIC_RELAXED, __HIP_MEMORY_SCOPE_AGENT);
    asm volatile("s_waitcnt vmcnt(0)" ::: "memory");
    __syncthreads();
    if (tid == 0)
      __hip_atomic_store(flags + ((t & 3) << 8) + (g << 4) + s, t + 1,
                         __ATOMIC_RELAXED, __HIP_MEMORY_SCOPE_AGENT);

    // ---- off-critical-path output writes ----------------------------------
    float2 hv; hv.x = h0; hv.y = h1;
    *(float2*)&out[(((gb << 9) + t) << 9) + ug] = hv;
    if (t == 511) {
      float2 cv; cv.x = c0; cv.y = c1;
      *(float2*)&out[HT_OFF + (gb << 9) + ug] = hv;
      *(float2*)&out[CT_OFF + (gb << 9) + ug] = cv;
    }
  }

  // ---- block 0: finalize deterministic loss sum ---------------------------
  if (bid == 0) {
    float v = partials[tid] + partials[tid + 256];
#pragma unroll
    for (int off = 32; off; off >>= 1) v += __shfl_down(v, off, 64);
    __shared__ float lw[4];
    if ((tid & 63) == 0) lw[tid >> 6] = v;
    __syncthreads();
    if (tid == 0) out[LOSS_OFF] = lw[0] + lw[1] + lw[2] + lw[3];
  }
}

// ---------------------------------------------------------------------------
extern "C" void kernel_launch(void* const* d_in, const int* in_sizes, int n_in,
                              void* d_out, int out_size, void* d_ws, size_t ws_size,
                              hipStream_t stream) {
  if (ws_size < WS_NEEDED) return;
  const float* x       = (const float*)d_in[0];
  const float* whh     = (const float*)d_in[1];
  const float* wih     = (const float*)d_in[2];
  const float* bias    = (const float*)d_in[3];
  const float* whh_mu  = (const float*)d_in[4];
  const float* whh_rho = (const float*)d_in[5];
  const float* wih_mu  = (const float*)d_in[6];
  const float* wih_rho = (const float*)d_in[7];
  const float* b_mu    = (const float*)d_in[8];
  const float* b_rho   = (const float*)d_in[9];
  char* ws = (char*)d_ws;
  unsigned short* w_frag = (unsigned short*)(ws + WFRAG_OFF);
  unsigned short* h_buf  = (unsigned short*)(ws + HBUF_OFF);
  int*            flags  = (int*)(ws + FLAGS_OFF);
  float*          parts  = (float*)(ws + PART_OFF);
  float*          out    = (float*)d_out;

  prep_w<<<640, 256, 0, stream>>>(whh, wih, w_frag, flags);
  loss_k<<<512, 256, 0, stream>>>(whh, wih, bias, whh_mu, whh_rho,
                                  wih_mu, wih_rho, b_mu, b_rho, parts);

  void* kargs[7];
  kargs[0] = (void*)&x;
  kargs[1] = (void*)&w_frag;
  kargs[2] = (void*)&bias;
  kargs[3] = (void*)&h_buf;
  kargs[4] = (void*)&flags;
  kargs[5] = (void*)&parts;
  kargs[6] = (void*)&out;
  hipLaunchCooperativeKernel((const void*)lstm_k, dim3(256), dim3(256),
                             kargs, 0, stream);
}